// Round 11
// baseline (103.652 us; speedup 1.0000x reference)
//
#include <hip/hip_runtime.h>

#define BATCH 65536
#define NSPL  64
#define CDIM  64
#define TDIM  68          // CDIM + DEGREE + 1
#define QI    67          // degree-0 intervals
#define RTN   67          // region-table entries per spline

#define TCOLS 16          // splines per block: full 64B line per row
#define TROWS 128         // rows per block (2 rows/lane/column)
#define NTHR  256
#define PITCH 129         // 129 % 32 == 1: compute-phase stride-1 reads free

// ============================================================================
// Sorted-region formulation (R8): S(x) piecewise-cubic; region index
// m = #{j: x >= t_j} over the ORIGINAL knots; RT[spline][m-1] float4 from
// prep (fp64); m=0/68 -> 0.
// R8/R9/R10 matrix: s_load feed@6blk (102.2), readlane@4blk (103.9),
// s_load+global-gather@8blk (100.8) -> each latency fix was confounded with
// occupancy. R11 removes ALL in-loop memory at full occupancy: knots in
// lane-resident VGPRs (8 coalesced loads/block), count loop readlane-fed
// (compile-time lanes after unroll), 4 columns FUSED -> 8 independent
// cmp+addc chains per wave, RT gathers issued 4-wide. Hot loop: zero s_load,
// zero ds_read, zero vmem. Pre-registered: null result (<3us) exonerates the
// compute path entirely -> residual is harness/graph-structural.
// ============================================================================

__global__ __launch_bounds__(128) void prep(const float* __restrict__ T,
                                            const float* __restrict__ C,
                                            float4* __restrict__ RT) {
    __shared__ double  td[TDIM];
    __shared__ double  cd[CDIM];
    __shared__ double  R1[QI], R2[TDIM - 2], R3[TDIM - 3];
    __shared__ double4 Qd[QI];
    __shared__ float   tf[TDIM];
    __shared__ float   srt[TDIM];

    const int s = blockIdx.x;
    const int t = threadIdx.x;

    if (t < TDIM) { float v = T[s * TDIM + t]; tf[t] = v; td[t] = (double)v; }
    if (t >= 64 && t < 64 + CDIM) cd[t - 64] = (double)C[s * CDIM + t - 64];
    __syncthreads();

    // Safe reciprocals (0/0 := 0; fp64 diff is 0 iff fp32 values equal).
    if (t < TDIM - 1) { double d = td[t + 1] - td[t]; R1[t] = (d == 0.0) ? 0.0 : 1.0 / d; }
    if (t < TDIM - 2) { double d = td[t + 2] - td[t]; R2[t] = (d == 0.0) ? 0.0 : 1.0 / d; }
    if (t < TDIM - 3) { double d = td[t + 3] - td[t]; R3[t] = (d == 0.0) ? 0.0 : 1.0 / d; }
    // Rank-sort the 68 knots (ties broken by index -> deterministic).
    if (t < TDIM) {
        float v = tf[t];
        int r = 0;
        for (int k = 0; k < TDIM; ++k)
            r += (tf[k] < v) || (tf[k] == v && k < t);
        srt[r] = v;
    }
    __syncthreads();

    // Expand Q_i: cubic for interval i, sum over <=8 Cox-de Boor lattice paths.
    if (t < QI) {
        const int i = t;
        double q0 = 0, q1 = 0, q2 = 0, q3 = 0;
        for (int j = i - 3; j <= i; ++j) {
            if (j < 0 || j > CDIM - 1) continue;
            double cj = cd[j];
            for (int b2 = 0; b2 < 2; ++b2) {
                int m2 = j + b2;
                double D3 = R3[j + b2];
                double p3 = b2 ? -D3 : D3;
                double r3 = b2 ? D3 * td[j + 4] : -D3 * td[j];
                for (int b1 = 0; b1 < 2; ++b1) {
                    int m1 = m2 + b1;
                    double D2 = R2[m2 + b1];
                    double p2 = b1 ? -D2 : D2;
                    double r2 = b1 ? D2 * td[m2 + 3] : -D2 * td[m2];
                    for (int b0 = 0; b0 < 2; ++b0) {
                        if (m1 + b0 != i) continue;   // path must end at interval i
                        double D1 = R1[m1 + b0];
                        double p1 = b0 ? -D1 : D1;
                        double r1 = b0 ? D1 * td[m1 + 2] : -D1 * td[m1];
                        double a2 = p3 * p2, a1 = p3 * r2 + r3 * p2, a0 = r3 * r2;
                        q3 += cj * (a2 * p1);
                        q2 += cj * (a2 * r1 + a1 * p1);
                        q1 += cj * (a1 * r1 + a0 * p1);
                        q0 += cj * (a0 * r1);
                    }
                }
            }
        }
        double4 q; q.x = q0; q.y = q1; q.z = q2; q.w = q3;
        Qd[i] = q;
    }
    __syncthreads();

    // Region sums: for m = t in 1..67, x* = srt[m-1]; active i <=> same fp32
    // predicates as the reference. Coefficient-wise fp64 sum -> fp32 cubic.
    if (t >= 1 && t <= RTN) {
        const float xs = srt[t - 1];
        double a0 = 0, a1 = 0, a2 = 0, a3 = 0;
        for (int i = 0; i < QI; ++i) {
            if (tf[i] <= xs && xs < tf[i + 1]) {
                double4 q = Qd[i];
                a0 += q.x; a1 += q.y; a2 += q.z; a3 += q.w;
            }
        }
        float4 v; v.x = (float)a0; v.y = (float)a1; v.z = (float)a2; v.w = (float)a3;
        RT[s * RTN + (t - 1)] = v;
    }
}

static __device__ __forceinline__ float rdlane(float v, int l) {
    return __builtin_bit_cast(float, __builtin_amdgcn_readlane(__builtin_bit_cast(int, v), l));
}

__global__ __launch_bounds__(NTHR) void bspline_main(const float* __restrict__ X,
                                                     const float* __restrict__ T,
                                                     const float4* __restrict__ RT,
                                                     float* __restrict__ O) {
    __shared__ float xl[TCOLS * PITCH];   // 8,256 B: x tile [col][row]; reused for out

    const int tid  = threadIdx.x;
    const int lane = tid & 63;
    const int w    = tid >> 6;
    const int r0   = blockIdx.x * TROWS;
    const int s0   = blockIdx.y * TCOLS;

    // Stage X tile: coalesced global (4 full 64B lines per wave-instr).
    #pragma unroll
    for (int it = 0; it < TROWS * TCOLS / NTHR; ++it) {   // 8 iters
        int e = tid + it * NTHR;
        int r = e >> 4, c = e & 15;
        xl[c * PITCH + r] = X[(r0 + r) * NSPL + s0 + c];
    }

    // Prefetch my 4 columns' knots into lane-resident VGPRs (8 coalesced
    // loads, one drain): kA[cc] lane j = t_j (j=0..63); kB[cc] lanes 0..3 =
    // t_64..t_67.
    float kA[4], kB[4];
    #pragma unroll
    for (int cc = 0; cc < 4; ++cc) {
        const int sp = s0 + w * 4 + cc;
        kA[cc] = T[sp * TDIM + lane];
        kB[cc] = T[sp * TDIM + 64 + (lane & 3)];
    }
    __syncthreads();

    // Load x for 2 rows x 4 cols (stride-1 LDS: conflict-free).
    float    xv0[4], xv1[4];
    unsigned n0[4], n1[4];
    #pragma unroll
    for (int cc = 0; cc < 4; ++cc) {
        const float* xc = xl + (w * 4 + cc) * PITCH + lane;
        xv0[cc] = xc[0];
        xv1[cc] = xc[64];
        n0[cc] = 0; n1[cc] = 0;
    }

    // FUSED count loop: per knot index, 4 readlane broadcasts feed 8
    // independent cmp+addc chains. ZERO memory ops, no s_load batches, no
    // lgkmcnt. Fully unrolled -> readlane lane operand is an immediate.
    #pragma unroll
    for (int j = 0; j < 64; ++j) {
        #pragma unroll
        for (int cc = 0; cc < 4; ++cc) {
            float tj = rdlane(kA[cc], j);
            n0[cc] += (xv0[cc] >= tj);
            n1[cc] += (xv1[cc] >= tj);
        }
    }
    #pragma unroll
    for (int j = 0; j < 4; ++j) {
        #pragma unroll
        for (int cc = 0; cc < 4; ++cc) {
            float tj = rdlane(kB[cc], j);
            n0[cc] += (xv0[cc] >= tj);
            n1[cc] += (xv1[cc] >= tj);
        }
    }

    // Gather + Horner, row-split (4 gathers in flight each) to cap VGPRs.
    // Region m = n; table entry m-1 for m in [1,67]; m=0/68 -> 0.
    #pragma unroll
    for (int half = 0; half < 2; ++half) {
        float*    xvp = half ? xv1 : xv0;
        unsigned* np  = half ? n1  : n0;
        float4 p[4];
        #pragma unroll
        for (int cc = 0; cc < 4; ++cc) {
            unsigned i = np[cc] - 1u;
            i = (i > 66u) ? 66u : i;            // wrap(n=0) -> 66 too (zeroed below)
            const int sp = s0 + w * 4 + cc;     // uniform
            p[cc] = RT[sp * RTN + i];           // divergent 16B gather, L1/L2 path
        }
        #pragma unroll
        for (int cc = 0; cc < 4; ++cc) {
            float x = xvp[cc];
            float y = fmaf(fmaf(fmaf(p[cc].w, x, p[cc].z), x, p[cc].y), x, p[cc].x);
            y = (np[cc] - 1u < 67u) ? y : 0.f;  // m=0 or m=68 -> outside all knots
            // In-place write-back: column owned by wave w; x reads done above.
            xl[(w * 4 + cc) * PITCH + lane + (half ? 64 : 0)] = y;
        }
    }
    __syncthreads();

    // Write out: full 64B lines per row.
    #pragma unroll
    for (int it = 0; it < TROWS * TCOLS / NTHR; ++it) {
        int e = tid + it * NTHR;
        int r = e >> 4, c = e & 15;
        O[(r0 + r) * NSPL + s0 + c] = xl[c * PITCH + r];
    }
}

extern "C" void kernel_launch(void* const* d_in, const int* in_sizes, int n_in,
                              void* d_out, int out_size, void* d_ws, size_t ws_size,
                              hipStream_t stream) {
    const float* X = (const float*)d_in[0];  // [65536, 64]
    const float* T = (const float*)d_in[1];  // [64, 68]
    const float* C = (const float*)d_in[2];  // [64, 64]
    float* O = (float*)d_out;                // [65536, 64]
    float4* RT = (float4*)d_ws;              // 64*67 float4 = 68,608 B

    prep<<<NSPL, 128, 0, stream>>>(T, C, RT);
    dim3 grid(BATCH / TROWS, NSPL / TCOLS);  // (512, 4) = 2048 blocks, 8/CU resident
    bspline_main<<<grid, NTHR, 0, stream>>>(X, T, RT, O);
}